// Round 15
// baseline (358.657 us; speedup 1.0000x reference)
//
#include <hip/hip_runtime.h>
#include <hip/hip_fp16.h>
#include <math.h>

#define NQ        14
#define DIM       16384          // 2^14
#define NLAYERS   5
#define NTHREADS  1024           // TWO batch elements per block, 512 threads each

typedef float vf2 __attribute__((ext_vector_type(2)));
struct c32 { float x, y; };

// GF(2)-LINEAR layout for 4B (half2) elements (r11-r14: 0 bank conflicts on HW).
__host__ __device__ constexpr int lswz5(int i) {
    return i ^ ((i >> 5) & 31) ^ ((i >> 10) & 15);
}
__host__ __device__ constexpr unsigned sjc(int j) {   // 5-bit adjacent-pair parity
    return (((j >> 4) & (j >> 3)) ^ ((j >> 3) & (j >> 2)) ^
            ((j >> 2) & (j >> 1)) ^ ((j >> 1) & j)) & 1u;
}
__host__ __device__ constexpr unsigned pjc(int j) {   // 4-bit adjacent-pair parity
    return (((j >> 3) & (j >> 2)) ^ ((j >> 2) & (j >> 1)) ^ ((j >> 1) & j)) & 1u;
}

__device__ __forceinline__ c32 cmul(c32 a, c32 b) {
    return { a.x * b.x - a.y * b.y, a.x * b.y + a.y * b.x };
}
__device__ __forceinline__ vf2 sxor(vf2 v, unsigned m) {
    return vf2{ __uint_as_float(__float_as_uint(v.x) ^ m),
                __uint_as_float(__float_as_uint(v.y) ^ m) };
}

// fp16 state pack/unpack (RTN).
__device__ __forceinline__ unsigned pk16(vf2 v) {
    __half2 h = __float22half2_rn(float2{ v.x, v.y });
    return *reinterpret_cast<unsigned*>(&h);
}
__device__ __forceinline__ vf2 up16(unsigned u) {
    __half2 h = *reinterpret_cast<__half2*>(&u);
    float2 f = __half22float2(h);
    return vf2{ f.x, f.y };
}

// Complex mult z' = g*z in 2 VOP3P (r7-proven pattern).
__device__ __forceinline__ vf2 cmulv(vf2 g, vf2 z) {
    vf2 o;
    asm("v_pk_mul_f32 %0, %1, %2 op_sel:[1,1] op_sel_hi:[1,0] neg_lo:[0,1] neg_hi:[0,0]\n\t"
        "v_pk_fma_f32 %0, %1, %2, %0 op_sel:[0,0,0] op_sel_hi:[0,1,1]"
        : "=&v"(o) : "v"(g), "v"(z));
    return o;
}

// REAL rotation butterfly in 4 VOP3P (r10-proven).
__device__ __forceinline__ void bfr(vf2 r, vf2& A0, vf2& A1) {
    vf2 b0, b1;
    asm("v_pk_mul_f32 %0, %2, %3 op_sel:[0,0] op_sel_hi:[0,1]\n\t"
        "v_pk_fma_f32 %0, %2, %4, %0 op_sel:[1,0,0] op_sel_hi:[1,1,1] neg_lo:[1,0,0] neg_hi:[1,0,0]\n\t"
        "v_pk_mul_f32 %1, %2, %3 op_sel:[1,0] op_sel_hi:[1,1]\n\t"
        "v_pk_fma_f32 %1, %2, %4, %1 op_sel:[0,0,0] op_sel_hi:[0,1,1]"
        : "=&v"(b0), "=&v"(b1)
        : "v"(r), "v"(A0), "v"(A1));
    A0 = b0; A1 = b1;
}

#define APPLY32R(K, RV) { const vf2 rv_ = (RV); _Pragma("unroll") \
    for (int mm = 0; mm < 16; ++mm) { \
        const int r0 = ((mm >> (K)) << ((K) + 1)) | (mm & ((1 << (K)) - 1)); \
        bfr(rv_, a[r0], a[r0 | (1 << (K))]); } }
#define APPLY16R(K, RV) { const vf2 rv_ = (RV); _Pragma("unroll") \
    for (int mm = 0; mm < 8; ++mm) { \
        const int r0 = ((mm >> (K)) << ((K) + 1)) | (mm & ((1 << (K)) - 1)); \
        bfr(rv_, aa[r0], aa[r0 | (1 << (K))]); } }

// Ring-sign masks (r8/r10, verified) — tl is the 9-bit within-state thread id.
#define AMASK(j) ((((j) & 1) ? (((j) & 16) ? M11 : M10) : (((j) & 16) ? M01 : M00)) \
                  ^ (sjc(j) << 31))
#define CMASK(v, j) ((((v)) ? (((j) & 8) ? C11 : C10) : (((j) & 8) ? C01 : C00)) \
                     ^ (((pjc(j) ^ ((j) & (v) & 1)) & 1u) << 31))

// ---- B pass: load, phase table, 5 real gates (q5..9), store ----
__device__ __forceinline__ void passB(char* stb, const vf2* GrL, const vf2* Tk, int base2) {
    vf2 a[32];
    #pragma unroll
    for (int j = 0; j < 32; ++j)
        a[j] = up16(*(const unsigned*)(stb + (base2 ^ (lswz5(j << 4) << 2))));
    #pragma unroll
    for (int j = 0; j < 32; ++j) a[j] = cmulv(Tk[j], a[j]);
    APPLY32R(4, GrL[5]); APPLY32R(3, GrL[6]); APPLY32R(2, GrL[7]);
    APPLY32R(1, GrL[8]); APPLY32R(0, GrL[9]);
    #pragma unroll
    for (int j = 0; j < 32; ++j)
        *(unsigned*)(stb + (base2 ^ (lswz5(j << 4) << 2))) = pk16(a[j]);
}

// ---- Fused A pass: Ta, gates la q0..4, ring sign, Tb, gates lb q0..4 ----
__device__ __forceinline__ void passAA(char* stb, const vf2* GrA, const vf2* GrB,
                                       const vf2* Ta, const vf2* Tb, int base1,
                                       unsigned M00, unsigned M01, unsigned M10, unsigned M11) {
    vf2 a[32];
    #pragma unroll
    for (int j = 0; j < 32; ++j)
        a[j] = up16(*(const unsigned*)(stb + (base1 ^ (lswz5(j << 9) << 2))));
    #pragma unroll
    for (int j = 0; j < 32; ++j) a[j] = cmulv(Ta[j], a[j]);
    APPLY32R(4, GrA[0]); APPLY32R(3, GrA[1]); APPLY32R(2, GrA[2]);
    APPLY32R(1, GrA[3]); APPLY32R(0, GrA[4]);
    #pragma unroll
    for (int j = 0; j < 32; ++j) a[j] = cmulv(Tb[j], sxor(a[j], AMASK(j)));
    APPLY32R(4, GrB[0]); APPLY32R(3, GrB[1]); APPLY32R(2, GrB[2]);
    APPLY32R(1, GrB[3]); APPLY32R(0, GrB[4]);
    #pragma unroll
    for (int j = 0; j < 32; ++j)
        *(unsigned*)(stb + (base1 ^ (lswz5(j << 9) << 2))) = pk16(a[j]);
}

// ---- Fused C pass: Ta, gates la q10..13, ring sign, Tb, gates lb q10..13 ----
__device__ __forceinline__ void passCC(char* stb, const vf2* GrA, const vf2* GrB,
                                       const vf2* Ta, const vf2* Tb, int base3,
                                       unsigned C00, unsigned C01, unsigned C10, unsigned C11) {
    #pragma unroll
    for (int v = 0; v < 2; ++v) {
        const int bb = base3 ^ (lswz5(v << 13) << 2);
        vf2 aa[16];
        #pragma unroll
        for (int j = 0; j < 16; ++j)
            aa[j] = up16(*(const unsigned*)(stb + (bb ^ (j << 2))));
        #pragma unroll
        for (int j = 0; j < 16; ++j) aa[j] = cmulv(Ta[j], aa[j]);
        APPLY16R(3, GrA[10]); APPLY16R(2, GrA[11]); APPLY16R(1, GrA[12]); APPLY16R(0, GrA[13]);
        #pragma unroll
        for (int j = 0; j < 16; ++j) aa[j] = cmulv(Tb[j], sxor(aa[j], CMASK(v, j)));
        APPLY16R(3, GrB[10]); APPLY16R(2, GrB[11]); APPLY16R(1, GrB[12]); APPLY16R(0, GrB[13]);
        #pragma unroll
        for (int j = 0; j < 16; ++j)
            *(unsigned*)(stb + (bb ^ (j << 2))) = pk16(aa[j]);
    }
}

// ---- Last C pass: Tk, gates l5 q10..13, |amp|^2 accumulate ----
__device__ __forceinline__ void passCLast(char* stb, const vf2* GrL, const vf2* Tk,
                                          int base3, float& se, float& so) {
    #pragma unroll
    for (int v = 0; v < 2; ++v) {
        const int bb = base3 ^ (lswz5(v << 13) << 2);
        vf2 aa[16];
        #pragma unroll
        for (int j = 0; j < 16; ++j)
            aa[j] = up16(*(const unsigned*)(stb + (bb ^ (j << 2))));
        #pragma unroll
        for (int j = 0; j < 16; ++j) aa[j] = cmulv(Tk[j], aa[j]);
        APPLY16R(3, GrL[10]); APPLY16R(2, GrL[11]); APPLY16R(1, GrL[12]); APPLY16R(0, GrL[13]);
        #pragma unroll
        for (int j = 0; j < 16; ++j) {
            const float d = fmaf(aa[j].x, aa[j].x, aa[j].y * aa[j].y);
            if (((v ^ __popc(j)) & 1) == 0) se += d; else so += d;
        }
    }
}

// ONE 16-wave workgroup holding TWO batch elements sidesteps the CP's
// inter-workgroup co-residency quirk (r11-r14: 2 blocks only at 64 VGPR).
// Intra-workgroup residency follows the HW file (m69): 4 waves/SIMD x 112 = 448
// <= 512. min=2 keeps the 256-reg codegen budget (r12/r13: 112 VGPR, no spill).
__attribute__((amdgpu_flat_work_group_size(NTHREADS, NTHREADS),
               amdgpu_waves_per_eu(2, 4)))
__global__ void pqc_kernel(
    const float* __restrict__ x,      // (B, 14)
    const float* __restrict__ theta,  // (252,)
    const float* __restrict__ lam,    // (70,)
    const float* __restrict__ w,      // (1, 2)
    float* __restrict__ out)          // (B, 2)
{
    __shared__ unsigned sth[2 * DIM];          // 128 KiB: two fp16x2 states
    __shared__ vf2 Gr[2][NLAYERS + 1][NQ];     // per-state (cos b/2, sin b/2)
    __shared__ vf2 Gang[2][NLAYERS + 1][NQ];   // per-state (a/2, c/2)
    __shared__ vf2 G0c[2][NQ][2];              // per-state layer-0 (u00, u10)
    __shared__ vf2 F0[2][5][2];                // per-state init factors
    __shared__ vf2 T[2][15][32];               // per-state phase tables
    __shared__ float wsum[16];

    const int t  = threadIdx.x;
    const int hs = t >> 9;                     // which of the 2 states
    const int tl = t & 511;                    // 9-bit within-state thread id
    const int b  = (blockIdx.x << 1) | hs;
    char* stb = (char*)sth + (hs << 16);       // 64 KiB per state

    // ---- Build: U (complex, enc fused) -> ZYZ decomposition (per state) ----
    if (tl < (NLAYERS + 1) * NQ) {
        const int l = tl / NQ, q = tl % NQ;
        const float a0 = theta[3 * tl + 0];
        const float a1 = theta[3 * tl + 1];
        const float a2t = theta[3 * tl + 2];
        const float cx = cosf(0.5f * a0), sx = sinf(0.5f * a0);
        const float cy = cosf(0.5f * a1), sy = sinf(0.5f * a1);
        const float cz = cosf(0.5f * a2t), sz = sinf(0.5f * a2t);
        const c32 m00 = {  cy * cx,  sy * sx };
        const c32 m01 = { -sy * cx, -cy * sx };
        const c32 m10 = {  sy * cx, -cy * sx };
        c32 u00 = { cz * m00.x + sz * m00.y,  cz * m00.y - sz * m00.x };
        c32 u01 = { cz * m01.x + sz * m01.y,  cz * m01.y - sz * m01.x };
        c32 u10 = { cz * m10.x - sz * m10.y,  cz * m10.y + sz * m10.x };
        if (l >= 1) {
            const float ang = x[b * NQ + q] * lam[(l - 1) * NQ + q];
            const float c = cosf(0.5f * ang), s = sinf(0.5f * ang);
            const c32 u11 = { u00.x, -u00.y };                    // SU(2)
            const c32 v00 = { u00.x * c + s * u01.y,  u00.y * c - s * u01.x };
            const c32 v10 = { u10.x * c + s * u11.y,  u10.y * c - s * u11.x };
            u00 = v00; u10 = v10;
        }
        if (l == 0) {
            G0c[hs][q][0] = vf2{ u00.x, u00.y };
            G0c[hs][q][1] = vf2{ u10.x, u10.y };
        }
        const float cb = sqrtf(u00.x * u00.x + u00.y * u00.y);
        const float sb = sqrtf(u10.x * u10.x + u10.y * u10.y);
        const float inv = rsqrtf(fmaxf(cb * cb + sb * sb, 1e-30f));
        const float p  = atan2f(u00.y, u00.x);
        const float qq = atan2f(u10.y, u10.x);
        Gr[hs][l][q]   = vf2{ cb * inv, sb * inv };
        Gang[hs][l][q] = vf2{ 0.5f * (qq - p), -0.5f * (p + qq) };  // (a/2, c/2)
    }
    __syncthreads();

    // ---- Boundary phase tables T[1..14]; init factors F0 (per state) ----
    if (tl < 448) {
        const int k = 1 + (tl >> 5), j = tl & 31;
        const int r = k % 6;
        const int win = (r == 0 || r == 5) ? 0 : ((r == 1 || r == 4) ? 1 : 2);
        if (win != 2 || j < 16) {
            const int lc = 1 + k / 3;
            const int lp = (k >= 3) ? lc - 1 : 0;
            const int nb = (win == 2) ? 4 : 5;
            float th = 0.f;
            for (int m = 0; m < nb; ++m) {
                const int q = (win == 0) ? (4 - m) : (win == 1) ? (9 - m) : (13 - m);
                float ww = Gang[hs][lc][q].y;
                if (lp) ww += Gang[hs][lp][q].x;
                th += ((j >> m) & 1) ? ww : -ww;
            }
            float sn, cn;
            __sincosf(th, &sn, &cn);
            T[hs][k][j] = vf2{ cn, sn };
        }
    } else if (tl < 458) {
        const int u = tl - 448, q = u >> 1, be = u & 1;
        const float c2 = Gang[hs][1][q].y;
        const float ph = be ? c2 : -c2;
        float sn, cn;
        __sincosf(ph, &sn, &cn);
        const vf2 g = G0c[hs][q][be];
        const c32 f = cmul(c32{ g.x, g.y }, c32{ cn, sn });
        F0[hs][q][be] = vf2{ f.x, f.y };
    }
    __syncthreads();

    // ---- Bases (byte offsets, 4B elements) & ring-sign words (from tl) ----
    const int base1 = lswz5(tl) << 2;
    const int base2 = lswz5(((tl & 0x1F0) << 5) | (tl & 15)) << 2;
    const int base3 = lswz5(tl << 4) << 2;
    const unsigned Pp  = (unsigned)(__popc(tl & (tl >> 1) & 0xFF) & 1);
    const unsigned t8 = (tl >> 8) & 1u, tb0 = tl & 1u;
    const unsigned M00 =  Pp              << 31;
    const unsigned M10 = (Pp ^ t8)        << 31;
    const unsigned M01 = (Pp ^ tb0)       << 31;
    const unsigned M11 = (Pp ^ t8 ^ tb0)  << 31;
    const unsigned C00 =  Pp              << 31;
    const unsigned C01 = (Pp ^ tb0)       << 31;
    const unsigned C10 = (Pp ^ t8)        << 31;
    const unsigned C11 = (Pp ^ t8 ^ tb0)  << 31;

    // ===== P1 (A window): analytic L0 (+DR_A1 via F0) + S1 + real A1 gates =====
    {
        c32 pref = { G0c[hs][5][(tl >> 8) & 1].x, G0c[hs][5][(tl >> 8) & 1].y };
        #pragma unroll
        for (int qq = 6; qq <= 13; ++qq) {
            const vf2 g = G0c[hs][qq][(tl >> (13 - qq)) & 1];
            pref = cmul(pref, c32{ g.x, g.y });
        }
        c32 p01p[4], p234[8];
        #pragma unroll
        for (int k = 0; k < 4; ++k) {
            const vf2 ga = F0[hs][0][k >> 1], gb = F0[hs][1][k & 1];
            p01p[k] = cmul(pref, cmul(c32{ ga.x, ga.y }, c32{ gb.x, gb.y }));
        }
        #pragma unroll
        for (int m = 0; m < 8; ++m) {
            const vf2 g2 = F0[hs][2][m >> 2], g3 = F0[hs][3][(m >> 1) & 1], g4 = F0[hs][4][m & 1];
            p234[m] = cmul(cmul(c32{ g2.x, g2.y }, c32{ g3.x, g3.y }), c32{ g4.x, g4.y });
        }
        vf2 a[32];
        #pragma unroll
        for (int j = 0; j < 32; ++j) {
            const c32 av = cmul(p01p[j >> 3], p234[j & 7]);
            a[j] = sxor(vf2{ av.x, av.y }, AMASK(j));
        }
        APPLY32R(4, Gr[hs][1][0]); APPLY32R(3, Gr[hs][1][1]); APPLY32R(2, Gr[hs][1][2]);
        APPLY32R(1, Gr[hs][1][3]); APPLY32R(0, Gr[hs][1][4]);
        #pragma unroll
        for (int j = 0; j < 32; ++j)
            *(unsigned*)(stb + (base1 ^ (lswz5(j << 9) << 2))) = pk16(a[j]);
    }
    __syncthreads();

    // ===== Fused 11-pass schedule with deferred-diagonal tables =====
    passB(stb, Gr[hs][1], T[hs][1], base2);                                       __syncthreads();
    passCC(stb, Gr[hs][1], Gr[hs][2], T[hs][2], T[hs][3], base3, C00, C01, C10, C11); __syncthreads();
    passB(stb, Gr[hs][2], T[hs][4], base2);                                       __syncthreads();
    passAA(stb, Gr[hs][2], Gr[hs][3], T[hs][5], T[hs][6], base1, M00, M01, M10, M11); __syncthreads();
    passB(stb, Gr[hs][3], T[hs][7], base2);                                       __syncthreads();
    passCC(stb, Gr[hs][3], Gr[hs][4], T[hs][8], T[hs][9], base3, C00, C01, C10, C11); __syncthreads();
    passB(stb, Gr[hs][4], T[hs][10], base2);                                      __syncthreads();
    passAA(stb, Gr[hs][4], Gr[hs][5], T[hs][11], T[hs][12], base1, M00, M01, M10, M11); __syncthreads();
    passB(stb, Gr[hs][5], T[hs][13], base2);                                      __syncthreads();
    float se = 0.f, so = 0.f;
    passCLast(stb, Gr[hs][5], T[hs][14], base3, se, so);

    // ---- Reduce + softmax (per state; waves never straddle states) ----
    float local = (__popc(tl) & 1) ? (so - se) : (se - so);
    #pragma unroll
    for (int off = 32; off > 0; off >>= 1)
        local += __shfl_down(local, off, 64);
    if ((t & 63) == 0) wsum[t >> 6] = local;
    __syncthreads();
    if (tl == 0) {
        float v = 0.0f;
        #pragma unroll
        for (int i = 0; i < 8; ++i) v += wsum[(hs << 3) + i];
        const float BETA = 1.0f;
        const float l0 = v * w[0] * BETA, l1 = v * w[1] * BETA;
        const float m  = fmaxf(l0, l1);
        const float e0 = __expf(l0 - m), e1 = __expf(l1 - m);
        const float inv = 1.0f / (e0 + e1);
        out[2 * b + 0] = e0 * inv;
        out[2 * b + 1] = e1 * inv;
    }
}

extern "C" void kernel_launch(void* const* d_in, const int* in_sizes, int n_in,
                              void* d_out, int out_size, void* d_ws, size_t ws_size,
                              hipStream_t stream) {
    const float* x     = (const float*)d_in[0];
    const float* theta = (const float*)d_in[1];
    const float* lam   = (const float*)d_in[2];
    const float* w     = (const float*)d_in[3];
    float* out = (float*)d_out;
    const int batch = in_sizes[0] / NQ;   // 2048
    pqc_kernel<<<batch / 2, NTHREADS, 0, stream>>>(x, theta, lam, w, out);
}

// Round 16
// 293.437 us; speedup vs baseline: 1.2223x; 1.2223x over previous
//
#include <hip/hip_runtime.h>
#include <hip/hip_fp16.h>
#include <math.h>

#define NQ        14
#define DIM       16384          // 2^14
#define NLAYERS   5
#define NTHREADS  512            // 32 amps/thread, processed 16-at-a-time (2 iters)

typedef float vf2 __attribute__((ext_vector_type(2)));
struct c32 { float x, y; };

// GF(2)-LINEAR layout for 4B (half2) elements (r11-r14: 0 bank conflicts on HW).
__host__ __device__ constexpr int lswz5(int i) {
    return i ^ ((i >> 5) & 31) ^ ((i >> 10) & 15);
}
// 4-bit adjacent-pair parity.
__host__ __device__ constexpr unsigned pjc(int j) {
    return (((j >> 3) & (j >> 2)) ^ ((j >> 2) & (j >> 1)) ^ ((j >> 1) & j)) & 1u;
}
// Compile-time j-part byte offset for window shift SH.
__host__ __device__ constexpr int OFSJ(int sh, int j) { return lswz5(j << sh) << 2; }
// Runtime w-part byte offsets: lswz5(1<<9)<<2 and lswz5(1<<13)<<2.
#define WOFS_A (((1 << 9) | (1 << 4)) << 2)
#define WOFS_T (((1 << 13) | (1 << 3)) << 2)

__device__ __forceinline__ c32 cmul(c32 a, c32 b) {
    return { a.x * b.x - a.y * b.y, a.x * b.y + a.y * b.x };
}
__device__ __forceinline__ vf2 sxor(vf2 v, unsigned m) {
    return vf2{ __uint_as_float(__float_as_uint(v.x) ^ m),
                __uint_as_float(__float_as_uint(v.y) ^ m) };
}
__device__ __forceinline__ unsigned pk16(vf2 v) {
    __half2 h = __float22half2_rn(float2{ v.x, v.y });
    return *reinterpret_cast<unsigned*>(&h);
}
__device__ __forceinline__ vf2 up16(unsigned u) {
    __half2 h = *reinterpret_cast<__half2*>(&u);
    float2 f = __half22float2(h);
    return vf2{ f.x, f.y };
}
// Complex mult z' = g*z in 2 VOP3P (r7-proven pattern).
__device__ __forceinline__ vf2 cmulv(vf2 g, vf2 z) {
    vf2 o;
    asm("v_pk_mul_f32 %0, %1, %2 op_sel:[1,1] op_sel_hi:[1,0] neg_lo:[0,1] neg_hi:[0,0]\n\t"
        "v_pk_fma_f32 %0, %1, %2, %0 op_sel:[0,0,0] op_sel_hi:[0,1,1]"
        : "=&v"(o) : "v"(g), "v"(z));
    return o;
}
// REAL rotation butterfly in 4 VOP3P (r10-proven).
__device__ __forceinline__ void bfr(vf2 r, vf2& A0, vf2& A1) {
    vf2 b0, b1;
    asm("v_pk_mul_f32 %0, %2, %3 op_sel:[0,0] op_sel_hi:[0,1]\n\t"
        "v_pk_fma_f32 %0, %2, %4, %0 op_sel:[1,0,0] op_sel_hi:[1,1,1] neg_lo:[1,0,0] neg_hi:[1,0,0]\n\t"
        "v_pk_mul_f32 %1, %2, %3 op_sel:[1,0] op_sel_hi:[1,1]\n\t"
        "v_pk_fma_f32 %1, %2, %4, %1 op_sel:[0,0,0] op_sel_hi:[0,1,1]"
        : "=&v"(b0), "=&v"(b1)
        : "v"(r), "v"(A0), "v"(A1));
    A0 = b0; A1 = b1;
}

#define APPLY16R(K, RV) { const vf2 rv_ = (RV); _Pragma("unroll") \
    for (int mm = 0; mm < 8; ++mm) { \
        const int r0 = ((mm >> (K)) << ((K) + 1)) | (mm & ((1 << (K)) - 1)); \
        bfr(rv_, aa[r0], aa[r0 | (1 << (K))]); } }

// Ring-sign mask, valid for BOTH the A window (i=(j<<10)|(w<<9)|t) and the D
// window (i=(w<<13)|(t<<4)|j): sign = Pt ^ (j0&w) ^ (w&t8) ^ (t0&j3) ^ pjc(j).
#define SMW(j) ((((j) & 1) ? (((j) & 8) ? s11 : s01) : (((j) & 8) ? s10 : s00)) \
                ^ (pjc(j) << 31))
#define SMASK_SETUP(w) \
    const unsigned s00 = (Pt ^ ((unsigned)(w) & t8)) << 31; \
    const unsigned s01 = s00 ^ ((unsigned)(w) << 31); \
    const unsigned s10 = s00 ^ (t0 << 31); \
    const unsigned s11 = s01 ^ (t0 << 31);

// ---- Plain 4-gate pass on window bits SH+3..SH (gates g4[0..3], hi->lo bit) ----
template<int SH>
__device__ __forceinline__ void pass4(char* stb, const vf2* g4, const vf2* Tk,
                                      int base) {
    #pragma unroll 1
    for (int w = 0; w < 2; ++w) {
        const int bb = base ^ (w ? WOFS_T : 0);
        vf2 aa[16];
        #pragma unroll
        for (int j = 0; j < 16; ++j)
            aa[j] = up16(*(const unsigned*)(stb + (bb ^ OFSJ(SH, j))));
        #pragma unroll
        for (int j = 0; j < 16; ++j) aa[j] = cmulv(Tk[j], aa[j]);
        APPLY16R(3, g4[0]); APPLY16R(2, g4[1]); APPLY16R(1, g4[2]); APPLY16R(0, g4[3]);
        #pragma unroll
        for (int j = 0; j < 16; ++j)
            *(unsigned*)(stb + (bb ^ OFSJ(SH, j))) = pk16(aa[j]);
    }
}

// ---- Fused A pass: Ta, gates la q0..3, ring sign, Tb, gates lb q0..3 ----
__device__ __forceinline__ void passAA(char* stb, const vf2* gA, const vf2* gB,
                                       const vf2* Ta, const vf2* Tb, int base,
                                       unsigned Pt, unsigned t8, unsigned t0) {
    #pragma unroll 1
    for (int w = 0; w < 2; ++w) {
        const int bb = base ^ (w ? WOFS_A : 0);
        SMASK_SETUP(w);
        vf2 aa[16];
        #pragma unroll
        for (int j = 0; j < 16; ++j)
            aa[j] = up16(*(const unsigned*)(stb + (bb ^ OFSJ(10, j))));
        #pragma unroll
        for (int j = 0; j < 16; ++j) aa[j] = cmulv(Ta[j], aa[j]);
        APPLY16R(3, gA[0]); APPLY16R(2, gA[1]); APPLY16R(1, gA[2]); APPLY16R(0, gA[3]);
        #pragma unroll
        for (int j = 0; j < 16; ++j) aa[j] = cmulv(Tb[j], sxor(aa[j], SMW(j)));
        APPLY16R(3, gB[0]); APPLY16R(2, gB[1]); APPLY16R(1, gB[2]); APPLY16R(0, gB[3]);
        #pragma unroll
        for (int j = 0; j < 16; ++j)
            *(unsigned*)(stb + (bb ^ OFSJ(10, j))) = pk16(aa[j]);
    }
}

// ---- Fused D pass: Ta, gates la q12,13, ring sign, Tb, gates lb q12,13 ----
__device__ __forceinline__ void passDD(char* stb, const vf2* gA, const vf2* gB,
                                       const vf2* Ta4, const vf2* Tb4, int base,
                                       unsigned Pt, unsigned t8, unsigned t0) {
    #pragma unroll 1
    for (int w = 0; w < 2; ++w) {
        const int bb = base ^ (w ? WOFS_T : 0);
        SMASK_SETUP(w);
        vf2 aa[16];
        #pragma unroll
        for (int j = 0; j < 16; ++j)
            aa[j] = up16(*(const unsigned*)(stb + (bb ^ OFSJ(0, j))));
        #pragma unroll
        for (int j = 0; j < 16; ++j) aa[j] = cmulv(Ta4[j & 3], aa[j]);
        APPLY16R(1, gA[0]); APPLY16R(0, gA[1]);
        #pragma unroll
        for (int j = 0; j < 16; ++j) aa[j] = cmulv(Tb4[j & 3], sxor(aa[j], SMW(j)));
        APPLY16R(1, gB[0]); APPLY16R(0, gB[1]);
        #pragma unroll
        for (int j = 0; j < 16; ++j)
            *(unsigned*)(stb + (bb ^ OFSJ(0, j))) = pk16(aa[j]);
    }
}

// ---- Last pass: Tk, gates l5 q12,13, |amp|^2 accumulate ----
__device__ __forceinline__ void passD5(char* stb, const vf2* g, const vf2* T4e,
                                       int base, float& se, float& so) {
    #pragma unroll 1
    for (int w = 0; w < 2; ++w) {
        const int bb = base ^ (w ? WOFS_T : 0);
        vf2 aa[16];
        #pragma unroll
        for (int j = 0; j < 16; ++j)
            aa[j] = up16(*(const unsigned*)(stb + (bb ^ OFSJ(0, j))));
        #pragma unroll
        for (int j = 0; j < 16; ++j) aa[j] = cmulv(T4e[j & 3], aa[j]);
        APPLY16R(1, g[0]); APPLY16R(0, g[1]);
        #pragma unroll
        for (int j = 0; j < 16; ++j) {
            const float d = fmaf(aa[j].x, aa[j].x, aa[j].y * aa[j].y);
            if (((w ^ __popc(j)) & 1) == 0) se += d; else so += d;
        }
    }
}

// 512 threads + waves_per_eu(4,4): 64-VGPR budget (r11-proven) AND the a[16]
// working set genuinely fits it -> no spill; HW co-schedules 2 blocks/CU at
// 64 VGPR (r11: 41.5% occupancy).
__attribute__((amdgpu_flat_work_group_size(NTHREADS, NTHREADS),
               amdgpu_waves_per_eu(4, 4)))
__global__ void pqc_kernel(
    const float* __restrict__ x,      // (B, 14)
    const float* __restrict__ theta,  // (252,)
    const float* __restrict__ lam,    // (70,)
    const float* __restrict__ w,      // (1, 2)
    float* __restrict__ out)          // (B, 2)
{
    __shared__ unsigned sth[DIM];              // 64 KiB fp16x2 state, layout L5(i)
    __shared__ vf2 Gr[NLAYERS + 1][NQ];        // (cos b/2, sin b/2)
    __shared__ vf2 Gang[NLAYERS + 1][NQ];      // (a/2, c/2)
    __shared__ vf2 G0c[NQ][2];                 // layer-0 (u00, u10)
    __shared__ vf2 F0[4][2];                   // init factors q0..3 incl DR(A,1)
    __shared__ vf2 T16[14][16];                // B:0-4, C:5-9, A:10-13
    __shared__ vf2 T4[5][4];                   // D tables
    __shared__ float wsum[NTHREADS / 64];

    const int t = threadIdx.x;
    const int b = blockIdx.x;
    char* stb = (char*)sth;

    // ---- Build: U (complex, enc fused) -> ZYZ decomposition (r13-verified) ----
    if (t < (NLAYERS + 1) * NQ) {
        const int l = t / NQ, q = t % NQ;
        const float a0 = theta[3 * t + 0];
        const float a1 = theta[3 * t + 1];
        const float a2t = theta[3 * t + 2];
        const float cx = cosf(0.5f * a0), sx = sinf(0.5f * a0);
        const float cy = cosf(0.5f * a1), sy = sinf(0.5f * a1);
        const float cz = cosf(0.5f * a2t), sz = sinf(0.5f * a2t);
        const c32 m00 = {  cy * cx,  sy * sx };
        const c32 m01 = { -sy * cx, -cy * sx };
        const c32 m10 = {  sy * cx, -cy * sx };
        c32 u00 = { cz * m00.x + sz * m00.y,  cz * m00.y - sz * m00.x };
        c32 u01 = { cz * m01.x + sz * m01.y,  cz * m01.y - sz * m01.x };
        c32 u10 = { cz * m10.x - sz * m10.y,  cz * m10.y + sz * m10.x };
        if (l >= 1) {
            const float ang = x[b * NQ + q] * lam[(l - 1) * NQ + q];
            const float c = cosf(0.5f * ang), s = sinf(0.5f * ang);
            const c32 u11 = { u00.x, -u00.y };                    // SU(2)
            const c32 v00 = { u00.x * c + s * u01.y,  u00.y * c - s * u01.x };
            const c32 v10 = { u10.x * c + s * u11.y,  u10.y * c - s * u11.x };
            u00 = v00; u10 = v10;
        }
        if (l == 0) {
            G0c[q][0] = vf2{ u00.x, u00.y };
            G0c[q][1] = vf2{ u10.x, u10.y };
        }
        const float cb = sqrtf(u00.x * u00.x + u00.y * u00.y);
        const float sb = sqrtf(u10.x * u10.x + u10.y * u10.y);
        const float inv = rsqrtf(fmaxf(cb * cb + sb * sb, 1e-30f));
        const float p  = atan2f(u00.y, u00.x);
        const float qq = atan2f(u10.y, u10.x);
        Gr[l][q]   = vf2{ cb * inv, sb * inv };
        Gang[l][q] = vf2{ 0.5f * (qq - p), -0.5f * (p + qq) };    // (a/2, c/2)
    }
    __syncthreads();

    // ---- Boundary phase tables (r10-verified convention: j bit m <-> qubit
    //      13-SH-m, +w if bit set, w = c2[lc][q] + a2[lp][q]) ----
    if (t < 224) {
        const int id = t >> 4, j = t & 15;
        int lp, lc, qb;
        if (id < 5)       { lp = id;     lc = id + 1; qb = 7;  }   // B: lc=1..5
        else if (id < 10) { lp = id - 5; lc = id - 4; qb = 11; }   // C: lc=1..5
        else              { lp = id - 9; lc = id - 8; qb = 3;  }   // A: lc=2..5
        float th = 0.f;
        for (int m = 0; m < 4; ++m) {
            const int q = qb - m;
            float ww = Gang[lc][q].y;
            if (lp) ww += Gang[lp][q].x;
            th += ((j >> m) & 1) ? ww : -ww;
        }
        float sn, cn; __sincosf(th, &sn, &cn);
        T16[id][j] = vf2{ cn, sn };
    } else if (t < 244) {
        const int u = t - 224, id = u >> 2, j = u & 3;            // D: lc=1..5
        const int lp = id, lc = id + 1;
        float th = 0.f;
        for (int m = 0; m < 2; ++m) {
            const int q = 13 - m;
            float ww = Gang[lc][q].y;
            if (lp) ww += Gang[lp][q].x;
            th += ((j >> m) & 1) ? ww : -ww;
        }
        float sn, cn; __sincosf(th, &sn, &cn);
        T4[id][j] = vf2{ cn, sn };
    } else if (t < 252) {
        const int u = t - 244, q = u >> 1, be = u & 1;            // F0: q0..3
        const float c2 = Gang[1][q].y;
        const float ph = be ? c2 : -c2;
        float sn, cn; __sincosf(ph, &sn, &cn);
        const vf2 g = G0c[q][be];
        const c32 f = cmul(c32{ g.x, g.y }, c32{ cn, sn });
        F0[q][be] = vf2{ f.x, f.y };
    }
    __syncthreads();

    // ---- Per-thread bases & ring-sign ingredients ----
    const int baseA = lswz5(t) << 2;                              // i=(j<<10)|(w<<9)|t
    const int baseB = lswz5(((t >> 6) << 10) | (t & 63)) << 2;    // i=..|j<<6|..
    const int baseC = lswz5(((t >> 2) << 6) | (t & 3)) << 2;      // i=..|j<<2|..
    const int baseD = lswz5(t << 4) << 2;                         // i=(w<<13)|(t<<4)|j
    const unsigned Pt = (unsigned)(__popc(t & (t >> 1) & 0xFF) & 1);
    const unsigned t8 = (t >> 8) & 1u, t0 = t & 1u;

    // ===== P1 (A window): analytic L0 (+DR(A,1) via F0) + s1 + A1 gates =====
    {
        c32 pref = { G0c[5][(t >> 8) & 1].x, G0c[5][(t >> 8) & 1].y };
        #pragma unroll
        for (int q = 6; q <= 13; ++q) {
            const vf2 g = G0c[q][(t >> (13 - q)) & 1];
            pref = cmul(pref, c32{ g.x, g.y });
        }
        #pragma unroll 1
        for (int w2 = 0; w2 < 2; ++w2) {
            const vf2 g4w = G0c[4][w2];
            const c32 prefw = cmul(pref, c32{ g4w.x, g4w.y });
            c32 pf01[4], pf23[4];
            #pragma unroll
            for (int k = 0; k < 4; ++k) {
                const vf2 fa = F0[0][(k >> 1) & 1], fb = F0[1][k & 1];
                const vf2 fc = F0[2][(k >> 1) & 1], fd = F0[3][k & 1];
                pf01[k] = cmul(prefw, cmul(c32{ fa.x, fa.y }, c32{ fb.x, fb.y }));
                pf23[k] = cmul(c32{ fc.x, fc.y }, c32{ fd.x, fd.y });
            }
            SMASK_SETUP(w2);
            vf2 aa[16];
            #pragma unroll
            for (int j = 0; j < 16; ++j) {
                const c32 av = cmul(pf01[(j >> 2) & 3], pf23[j & 3]);
                aa[j] = sxor(vf2{ av.x, av.y }, SMW(j));
            }
            APPLY16R(3, Gr[1][0]); APPLY16R(2, Gr[1][1]);
            APPLY16R(1, Gr[1][2]); APPLY16R(0, Gr[1][3]);
            const int bb = baseA ^ (w2 ? WOFS_A : 0);
            #pragma unroll
            for (int j = 0; j < 16; ++j)
                *(unsigned*)(stb + (bb ^ OFSJ(10, j))) = pk16(aa[j]);
        }
    }
    __syncthreads();

    // ===== Fused 16-pass schedule =====
    pass4<6>(stb, &Gr[1][4], T16[0], baseB);                            __syncthreads();
    pass4<2>(stb, &Gr[1][8], T16[5], baseC);                            __syncthreads();
    passDD(stb, &Gr[1][12], &Gr[2][12], T4[0], T4[1], baseD, Pt, t8, t0); __syncthreads();
    pass4<2>(stb, &Gr[2][8], T16[6], baseC);                            __syncthreads();
    pass4<6>(stb, &Gr[2][4], T16[1], baseB);                            __syncthreads();
    passAA(stb, &Gr[2][0], &Gr[3][0], T16[10], T16[11], baseA, Pt, t8, t0); __syncthreads();
    pass4<6>(stb, &Gr[3][4], T16[2], baseB);                            __syncthreads();
    pass4<2>(stb, &Gr[3][8], T16[7], baseC);                            __syncthreads();
    passDD(stb, &Gr[3][12], &Gr[4][12], T4[2], T4[3], baseD, Pt, t8, t0); __syncthreads();
    pass4<2>(stb, &Gr[4][8], T16[8], baseC);                            __syncthreads();
    pass4<6>(stb, &Gr[4][4], T16[3], baseB);                            __syncthreads();
    passAA(stb, &Gr[4][0], &Gr[5][0], T16[12], T16[13], baseA, Pt, t8, t0); __syncthreads();
    pass4<6>(stb, &Gr[5][4], T16[4], baseB);                            __syncthreads();
    pass4<2>(stb, &Gr[5][8], T16[9], baseC);                            __syncthreads();
    float se = 0.f, so = 0.f;
    passD5(stb, &Gr[5][12], T4[4], baseD, se, so);

    // ---- Reduce + softmax ----
    float local = (__popc(t) & 1) ? (so - se) : (se - so);
    #pragma unroll
    for (int off = 32; off > 0; off >>= 1)
        local += __shfl_down(local, off, 64);
    if ((t & 63) == 0) wsum[t >> 6] = local;
    __syncthreads();
    if (t == 0) {
        float v = 0.0f;
        #pragma unroll
        for (int i = 0; i < NTHREADS / 64; ++i) v += wsum[i];
        const float BETA = 1.0f;
        const float l0 = v * w[0] * BETA, l1 = v * w[1] * BETA;
        const float m  = fmaxf(l0, l1);
        const float e0 = __expf(l0 - m), e1 = __expf(l1 - m);
        const float inv = 1.0f / (e0 + e1);
        out[2 * b + 0] = e0 * inv;
        out[2 * b + 1] = e1 * inv;
    }
}

extern "C" void kernel_launch(void* const* d_in, const int* in_sizes, int n_in,
                              void* d_out, int out_size, void* d_ws, size_t ws_size,
                              hipStream_t stream) {
    const float* x     = (const float*)d_in[0];
    const float* theta = (const float*)d_in[1];
    const float* lam   = (const float*)d_in[2];
    const float* w     = (const float*)d_in[3];
    float* out = (float*)d_out;
    const int batch = in_sizes[0] / NQ;   // 2048
    pqc_kernel<<<batch, NTHREADS, 0, stream>>>(x, theta, lam, w, out);
}

// Round 17
// 262.740 us; speedup vs baseline: 1.3651x; 1.1168x over previous
//
#include <hip/hip_runtime.h>
#include <hip/hip_fp16.h>
#include <math.h>

#define NQ        14
#define DIM       16384          // 2^14
#define NLAYERS   5
#define NTHREADS  512            // 32 amps/thread

typedef float vf2 __attribute__((ext_vector_type(2)));
struct c32 { float x, y; };

// GF(2)-LINEAR layout for 4B (half2) elements: sigma from bits>=5 into bits 4:0.
// L5(a^b)=L5(a)^L5(b). Verified 0 bank conflicts on HW (r11/r12 counters).
__host__ __device__ constexpr int lswz5(int i) {
    return i ^ ((i >> 5) & 31) ^ ((i >> 10) & 15);
}
__host__ __device__ constexpr unsigned sjc(int j) {   // 5-bit adjacent-pair parity
    return (((j >> 4) & (j >> 3)) ^ ((j >> 3) & (j >> 2)) ^
            ((j >> 2) & (j >> 1)) ^ ((j >> 1) & j)) & 1u;
}
__host__ __device__ constexpr unsigned pjc(int j) {   // 4-bit adjacent-pair parity
    return (((j >> 3) & (j >> 2)) ^ ((j >> 2) & (j >> 1)) ^ ((j >> 1) & j)) & 1u;
}

__device__ __forceinline__ c32 cmul(c32 a, c32 b) {
    return { a.x * b.x - a.y * b.y, a.x * b.y + a.y * b.x };
}
__device__ __forceinline__ vf2 sxor(vf2 v, unsigned m) {
    return vf2{ __uint_as_float(__float_as_uint(v.x) ^ m),
                __uint_as_float(__float_as_uint(v.y) ^ m) };
}

// fp16 state pack/unpack (RTN).
__device__ __forceinline__ unsigned pk16(vf2 v) {
    __half2 h = __float22half2_rn(float2{ v.x, v.y });
    return *reinterpret_cast<unsigned*>(&h);
}
__device__ __forceinline__ vf2 up16(unsigned u) {
    __half2 h = *reinterpret_cast<__half2*>(&u);
    float2 f = __half22float2(h);
    return vf2{ f.x, f.y };
}

// Complex mult z' = g*z in 2 VOP3P (r7-proven pattern).
__device__ __forceinline__ vf2 cmulv(vf2 g, vf2 z) {
    vf2 o;
    asm("v_pk_mul_f32 %0, %1, %2 op_sel:[1,1] op_sel_hi:[1,0] neg_lo:[0,1] neg_hi:[0,0]\n\t"
        "v_pk_fma_f32 %0, %1, %2, %0 op_sel:[0,0,0] op_sel_hi:[0,1,1]"
        : "=&v"(o) : "v"(g), "v"(z));
    return o;
}

// REAL rotation butterfly in 4 VOP3P (r10-proven).
__device__ __forceinline__ void bfr(vf2 r, vf2& A0, vf2& A1) {
    vf2 b0, b1;
    asm("v_pk_mul_f32 %0, %2, %3 op_sel:[0,0] op_sel_hi:[0,1]\n\t"
        "v_pk_fma_f32 %0, %2, %4, %0 op_sel:[1,0,0] op_sel_hi:[1,1,1] neg_lo:[1,0,0] neg_hi:[1,0,0]\n\t"
        "v_pk_mul_f32 %1, %2, %3 op_sel:[1,0] op_sel_hi:[1,1]\n\t"
        "v_pk_fma_f32 %1, %2, %4, %1 op_sel:[0,0,0] op_sel_hi:[0,1,1]"
        : "=&v"(b0), "=&v"(b1)
        : "v"(r), "v"(A0), "v"(A1));
    A0 = b0; A1 = b1;
}

#define APPLY32R(K, RV) { const vf2 rv_ = (RV); _Pragma("unroll") \
    for (int mm = 0; mm < 16; ++mm) { \
        const int r0 = ((mm >> (K)) << ((K) + 1)) | (mm & ((1 << (K)) - 1)); \
        bfr(rv_, a[r0], a[r0 | (1 << (K))]); } }
#define APPLY16R(K, RV) { const vf2 rv_ = (RV); _Pragma("unroll") \
    for (int mm = 0; mm < 8; ++mm) { \
        const int r0 = ((mm >> (K)) << ((K) + 1)) | (mm & ((1 << (K)) - 1)); \
        bfr(rv_, aa[r0], aa[r0 | (1 << (K))]); } }

// Ring-sign masks (r8/r10, verified).
#define AMASK(j) ((((j) & 1) ? (((j) & 16) ? M11 : M10) : (((j) & 16) ? M01 : M00)) \
                  ^ (sjc(j) << 31))
#define CMASK(v, j) ((((v)) ? (((j) & 8) ? C11 : C10) : (((j) & 8) ? C01 : C00)) \
                     ^ (((pjc(j) ^ ((j) & (v) & 1)) & 1u) << 31))

// ---- B pass: load, phase table, 5 real gates (q5..9), store ----
__device__ __forceinline__ void passB(char* stb, const vf2* GrL, const vf2* Tk, int base2) {
    vf2 a[32];
    #pragma unroll
    for (int j = 0; j < 32; ++j)
        a[j] = up16(*(const unsigned*)(stb + (base2 ^ (lswz5(j << 4) << 2))));
    #pragma unroll
    for (int j = 0; j < 32; ++j) a[j] = cmulv(Tk[j], a[j]);
    APPLY32R(4, GrL[5]); APPLY32R(3, GrL[6]); APPLY32R(2, GrL[7]);
    APPLY32R(1, GrL[8]); APPLY32R(0, GrL[9]);
    #pragma unroll
    for (int j = 0; j < 32; ++j)
        *(unsigned*)(stb + (base2 ^ (lswz5(j << 4) << 2))) = pk16(a[j]);
}

// ---- Fused A pass: Ta, gates la q0..4, ring sign, Tb, gates lb q0..4 ----
__device__ __forceinline__ void passAA(char* stb, const vf2* GrA, const vf2* GrB,
                                       const vf2* Ta, const vf2* Tb, int base1,
                                       unsigned M00, unsigned M01, unsigned M10, unsigned M11) {
    vf2 a[32];
    #pragma unroll
    for (int j = 0; j < 32; ++j)
        a[j] = up16(*(const unsigned*)(stb + (base1 ^ (lswz5(j << 9) << 2))));
    #pragma unroll
    for (int j = 0; j < 32; ++j) a[j] = cmulv(Ta[j], a[j]);
    APPLY32R(4, GrA[0]); APPLY32R(3, GrA[1]); APPLY32R(2, GrA[2]);
    APPLY32R(1, GrA[3]); APPLY32R(0, GrA[4]);
    #pragma unroll
    for (int j = 0; j < 32; ++j) a[j] = cmulv(Tb[j], sxor(a[j], AMASK(j)));
    APPLY32R(4, GrB[0]); APPLY32R(3, GrB[1]); APPLY32R(2, GrB[2]);
    APPLY32R(1, GrB[3]); APPLY32R(0, GrB[4]);
    #pragma unroll
    for (int j = 0; j < 32; ++j)
        *(unsigned*)(stb + (base1 ^ (lswz5(j << 9) << 2))) = pk16(a[j]);
}

// ---- Fused C pass: Ta, gates la q10..13, ring sign, Tb, gates lb q10..13 ----
__device__ __forceinline__ void passCC(char* stb, const vf2* GrA, const vf2* GrB,
                                       const vf2* Ta, const vf2* Tb, int base3,
                                       unsigned C00, unsigned C01, unsigned C10, unsigned C11) {
    #pragma unroll
    for (int v = 0; v < 2; ++v) {
        const int bb = base3 ^ (lswz5(v << 13) << 2);
        vf2 aa[16];
        #pragma unroll
        for (int j = 0; j < 16; ++j)
            aa[j] = up16(*(const unsigned*)(stb + (bb ^ (j << 2))));
        #pragma unroll
        for (int j = 0; j < 16; ++j) aa[j] = cmulv(Ta[j], aa[j]);
        APPLY16R(3, GrA[10]); APPLY16R(2, GrA[11]); APPLY16R(1, GrA[12]); APPLY16R(0, GrA[13]);
        #pragma unroll
        for (int j = 0; j < 16; ++j) aa[j] = cmulv(Tb[j], sxor(aa[j], CMASK(v, j)));
        APPLY16R(3, GrB[10]); APPLY16R(2, GrB[11]); APPLY16R(1, GrB[12]); APPLY16R(0, GrB[13]);
        #pragma unroll
        for (int j = 0; j < 16; ++j)
            *(unsigned*)(stb + (bb ^ (j << 2))) = pk16(aa[j]);
    }
}

// ---- Last C pass: Tk, gates l5 q10..13, |amp|^2 accumulate ----
__device__ __forceinline__ void passCLast(char* stb, const vf2* GrL, const vf2* Tk,
                                          int base3, float& se, float& so) {
    #pragma unroll
    for (int v = 0; v < 2; ++v) {
        const int bb = base3 ^ (lswz5(v << 13) << 2);
        vf2 aa[16];
        #pragma unroll
        for (int j = 0; j < 16; ++j)
            aa[j] = up16(*(const unsigned*)(stb + (bb ^ (j << 2))));
        #pragma unroll
        for (int j = 0; j < 16; ++j) aa[j] = cmulv(Tk[j], aa[j]);
        APPLY16R(3, GrL[10]); APPLY16R(2, GrL[11]); APPLY16R(1, GrL[12]); APPLY16R(0, GrL[13]);
        #pragma unroll
        for (int j = 0; j < 16; ++j) {
            const float d = fmaf(aa[j].x, aa[j].x, aa[j].y * aa[j].y);
            if (((v ^ __popc(j)) & 1) == 0) se += d; else so += d;
        }
    }
}

// r11 configuration (best measured: 263 us timed): 64-VGPR codegen + HW
// co-schedules 2 blocks/CU (41.5% occ); the a[32] spill is mostly L2-absorbed
// (FETCH 22 MB; ~146 B/thread reaches HBM) and beats every clean 1-block variant.
__attribute__((amdgpu_flat_work_group_size(NTHREADS, NTHREADS),
               amdgpu_waves_per_eu(4, 4)))
__global__ void pqc_kernel(
    const float* __restrict__ x,      // (B, 14)
    const float* __restrict__ theta,  // (252,)
    const float* __restrict__ lam,    // (70,)
    const float* __restrict__ w,      // (1, 2)
    float* __restrict__ out)          // (B, 2)
{
    __shared__ unsigned sth[DIM];              // 64 KiB fp16x2 state, layout L5(i)
    __shared__ vf2 Gr[NLAYERS + 1][NQ];        // (cos b/2, sin b/2)
    __shared__ vf2 Gang[NLAYERS + 1][NQ];      // (a/2, c/2)
    __shared__ vf2 G0c[NQ][2];                 // layer-0 (u00, u10)
    __shared__ vf2 F0[5][2];                   // init factors q0..4 incl DR_A1
    __shared__ vf2 T[15][32];                  // boundary phase tables
    __shared__ float wsum[NTHREADS / 64];

    const int t = threadIdx.x;
    const int b = blockIdx.x;
    char* stb = (char*)sth;

    // ---- Build: U (complex, enc fused) -> ZYZ decomposition ----
    if (t < (NLAYERS + 1) * NQ) {
        const int l = t / NQ, q = t % NQ;
        const float a0 = theta[3 * t + 0];
        const float a1 = theta[3 * t + 1];
        const float a2t = theta[3 * t + 2];
        const float cx = cosf(0.5f * a0), sx = sinf(0.5f * a0);
        const float cy = cosf(0.5f * a1), sy = sinf(0.5f * a1);
        const float cz = cosf(0.5f * a2t), sz = sinf(0.5f * a2t);
        const c32 m00 = {  cy * cx,  sy * sx };
        const c32 m01 = { -sy * cx, -cy * sx };
        const c32 m10 = {  sy * cx, -cy * sx };
        c32 u00 = { cz * m00.x + sz * m00.y,  cz * m00.y - sz * m00.x };
        c32 u01 = { cz * m01.x + sz * m01.y,  cz * m01.y - sz * m01.x };
        c32 u10 = { cz * m10.x - sz * m10.y,  cz * m10.y + sz * m10.x };
        if (l >= 1) {
            const float ang = x[b * NQ + q] * lam[(l - 1) * NQ + q];
            const float c = cosf(0.5f * ang), s = sinf(0.5f * ang);
            const c32 u11 = { u00.x, -u00.y };                    // SU(2)
            const c32 v00 = { u00.x * c + s * u01.y,  u00.y * c - s * u01.x };
            const c32 v10 = { u10.x * c + s * u11.y,  u10.y * c - s * u11.x };
            u00 = v00; u10 = v10;
        }
        if (l == 0) {
            G0c[q][0] = vf2{ u00.x, u00.y };
            G0c[q][1] = vf2{ u10.x, u10.y };
        }
        const float cb = sqrtf(u00.x * u00.x + u00.y * u00.y);
        const float sb = sqrtf(u10.x * u10.x + u10.y * u10.y);
        const float inv = rsqrtf(fmaxf(cb * cb + sb * sb, 1e-30f));
        const float p  = atan2f(u00.y, u00.x);
        const float qq = atan2f(u10.y, u10.x);
        Gr[l][q]   = vf2{ cb * inv, sb * inv };
        Gang[l][q] = vf2{ 0.5f * (qq - p), -0.5f * (p + qq) };    // (a/2, c/2)
    }
    __syncthreads();

    // ---- Boundary phase tables T[1..14]; init factors F0 ----
    if (t < 448) {
        const int k = 1 + (t >> 5), j = t & 31;
        const int r = k % 6;
        const int win = (r == 0 || r == 5) ? 0 : ((r == 1 || r == 4) ? 1 : 2);
        if (win != 2 || j < 16) {
            const int lc = 1 + k / 3;
            const int lp = (k >= 3) ? lc - 1 : 0;
            const int nb = (win == 2) ? 4 : 5;
            float th = 0.f;
            for (int m = 0; m < nb; ++m) {
                const int q = (win == 0) ? (4 - m) : (win == 1) ? (9 - m) : (13 - m);
                float ww = Gang[lc][q].y;
                if (lp) ww += Gang[lp][q].x;
                th += ((j >> m) & 1) ? ww : -ww;
            }
            float sn, cn;
            __sincosf(th, &sn, &cn);
            T[k][j] = vf2{ cn, sn };
        }
    } else if (t < 458) {
        const int u = t - 448, q = u >> 1, be = u & 1;
        const float c2 = Gang[1][q].y;
        const float ph = be ? c2 : -c2;
        float sn, cn;
        __sincosf(ph, &sn, &cn);
        const vf2 g = G0c[q][be];
        const c32 f = cmul(c32{ g.x, g.y }, c32{ cn, sn });
        F0[q][be] = vf2{ f.x, f.y };
    }
    __syncthreads();

    // ---- Bases (byte offsets, 4B elements) & ring-sign words ----
    const int base1 = lswz5(t) << 2;
    const int base2 = lswz5(((t & 0x1F0) << 5) | (t & 15)) << 2;
    const int base3 = lswz5(t << 4) << 2;
    const unsigned Pp  = (unsigned)(__popc(t & (t >> 1) & 0xFF) & 1);
    const unsigned t8 = (t >> 8) & 1u, tb0 = t & 1u;
    const unsigned M00 =  Pp              << 31;
    const unsigned M10 = (Pp ^ t8)        << 31;
    const unsigned M01 = (Pp ^ tb0)       << 31;
    const unsigned M11 = (Pp ^ t8 ^ tb0)  << 31;
    const unsigned C00 =  Pp              << 31;
    const unsigned C01 = (Pp ^ tb0)       << 31;
    const unsigned C10 = (Pp ^ t8)        << 31;
    const unsigned C11 = (Pp ^ t8 ^ tb0)  << 31;

    // ===== P1 (A window): analytic L0 (+DR_A1 via F0) + S1 + real A1 gates =====
    {
        c32 pref = { G0c[5][(t >> 8) & 1].x, G0c[5][(t >> 8) & 1].y };
        #pragma unroll
        for (int qq = 6; qq <= 13; ++qq) {
            const vf2 g = G0c[qq][(t >> (13 - qq)) & 1];
            pref = cmul(pref, c32{ g.x, g.y });
        }
        c32 p01p[4], p234[8];
        #pragma unroll
        for (int k = 0; k < 4; ++k) {
            const vf2 ga = F0[0][k >> 1], gb = F0[1][k & 1];
            p01p[k] = cmul(pref, cmul(c32{ ga.x, ga.y }, c32{ gb.x, gb.y }));
        }
        #pragma unroll
        for (int m = 0; m < 8; ++m) {
            const vf2 g2 = F0[2][m >> 2], g3 = F0[3][(m >> 1) & 1], g4 = F0[4][m & 1];
            p234[m] = cmul(cmul(c32{ g2.x, g2.y }, c32{ g3.x, g3.y }), c32{ g4.x, g4.y });
        }
        vf2 a[32];
        #pragma unroll
        for (int j = 0; j < 32; ++j) {
            const c32 av = cmul(p01p[j >> 3], p234[j & 7]);
            a[j] = sxor(vf2{ av.x, av.y }, AMASK(j));
        }
        APPLY32R(4, Gr[1][0]); APPLY32R(3, Gr[1][1]); APPLY32R(2, Gr[1][2]);
        APPLY32R(1, Gr[1][3]); APPLY32R(0, Gr[1][4]);
        #pragma unroll
        for (int j = 0; j < 32; ++j)
            *(unsigned*)(stb + (base1 ^ (lswz5(j << 9) << 2))) = pk16(a[j]);
    }
    __syncthreads();

    // ===== Fused 11-pass schedule with deferred-diagonal tables =====
    passB(stb, Gr[1], T[1], base2);                                        __syncthreads();
    passCC(stb, Gr[1], Gr[2], T[2], T[3], base3, C00, C01, C10, C11);      __syncthreads();
    passB(stb, Gr[2], T[4], base2);                                        __syncthreads();
    passAA(stb, Gr[2], Gr[3], T[5], T[6], base1, M00, M01, M10, M11);      __syncthreads();
    passB(stb, Gr[3], T[7], base2);                                        __syncthreads();
    passCC(stb, Gr[3], Gr[4], T[8], T[9], base3, C00, C01, C10, C11);      __syncthreads();
    passB(stb, Gr[4], T[10], base2);                                       __syncthreads();
    passAA(stb, Gr[4], Gr[5], T[11], T[12], base1, M00, M01, M10, M11);    __syncthreads();
    passB(stb, Gr[5], T[13], base2);                                       __syncthreads();
    float se = 0.f, so = 0.f;
    passCLast(stb, Gr[5], T[14], base3, se, so);

    // ---- Reduce + softmax ----
    float local = (__popc(t) & 1) ? (so - se) : (se - so);
    #pragma unroll
    for (int off = 32; off > 0; off >>= 1)
        local += __shfl_down(local, off, 64);
    if ((t & 63) == 0) wsum[t >> 6] = local;
    __syncthreads();
    if (t == 0) {
        float v = 0.0f;
        #pragma unroll
        for (int i = 0; i < NTHREADS / 64; ++i) v += wsum[i];
        const float BETA = 1.0f;
        const float l0 = v * w[0] * BETA, l1 = v * w[1] * BETA;
        const float m  = fmaxf(l0, l1);
        const float e0 = __expf(l0 - m), e1 = __expf(l1 - m);
        const float inv = 1.0f / (e0 + e1);
        out[2 * b + 0] = e0 * inv;
        out[2 * b + 1] = e1 * inv;
    }
}

extern "C" void kernel_launch(void* const* d_in, const int* in_sizes, int n_in,
                              void* d_out, int out_size, void* d_ws, size_t ws_size,
                              hipStream_t stream) {
    const float* x     = (const float*)d_in[0];
    const float* theta = (const float*)d_in[1];
    const float* lam   = (const float*)d_in[2];
    const float* w     = (const float*)d_in[3];
    float* out = (float*)d_out;
    const int batch = in_sizes[0] / NQ;   // 2048
    pqc_kernel<<<batch, NTHREADS, 0, stream>>>(x, theta, lam, w, out);
}